// Round 9
// baseline (900.247 us; speedup 1.0000x reference)
//
#include <hip/hip_runtime.h>
#include <hip/hip_bf16.h>
#include <math.h>

// CRF forward, B=512,S=512,C=96. One 64-lane wave per 16 chains (32 blocks).
// Step = (16x96)·(96x96) via 18x mfma_f32_16x16x32_f16 (layouts verified R8).
// R9: all streamed data (emissions, masks) staged through LDS by
// global_load_lds DMA (zero VGPR cost, compiler cannot sink it); arrival
// gated by explicit s_waitcnt vmcnt(14) (7 ops/step, distance 2, FIFO).
// Loop body has NO compiler global loads -> no stray vmcnt(0) drains.
// C->A transpose via f32 LDS (row stride 97 dwords: conflict-light),
// row max on reader side via 2x ds_bpermute. Exact power-of-2 renorm,
// integer exponent sum (R8 numerics, absmax 0.0).

#define BATCH 512
#define SEQ   512
#define NC    96
#define CH    16
#define NBLK  (BATCH / CH)   // 32
#define WLP   97             // wl row stride in dwords
#define LN2   0.69314718055994531f
#define LN2X4 2.7725887222397812f

typedef __fp16 half2v __attribute__((ext_vector_type(2)));
typedef __fp16 half8v __attribute__((ext_vector_type(8)));
typedef float  f32x4  __attribute__((ext_vector_type(4)));

typedef const unsigned __attribute__((address_space(1)))* gp1_t;
typedef unsigned __attribute__((address_space(3)))*       lp3_t;

__device__ __forceinline__ void load_lds16(const void* g, void* l) {
    __builtin_amdgcn_global_load_lds((gp1_t)g, (lp3_t)l, 16, 0, 0);
}
__device__ __forceinline__ void load_lds4(const void* g, void* l) {
    __builtin_amdgcn_global_load_lds((gp1_t)g, (lp3_t)l, 4, 0, 0);
}

#define DPP_STEP_F(v, op, ctrl)                                              \
    v = op(v, __int_as_float(__builtin_amdgcn_update_dpp(                    \
            __float_as_int(v), __float_as_int(v), (ctrl), 0xf, 0xf, false)))

__device__ __forceinline__ float fadd_(float a, float b) { return a + b; }
__device__ __forceinline__ float wave_sum_all(float v) {
    DPP_STEP_F(v, fadd_, 0x111);
    DPP_STEP_F(v, fadd_, 0x112);
    DPP_STEP_F(v, fadd_, 0x114);
    DPP_STEP_F(v, fadd_, 0x118);
    DPP_STEP_F(v, fadd_, 0x142);
    DPP_STEP_F(v, fadd_, 0x143);
    return __int_as_float(__builtin_amdgcn_readlane(__float_as_int(v), 63));
}
__device__ __forceinline__ float bperm_f(int lanesrc, float v) {
    return __int_as_float(__builtin_amdgcn_ds_bpermute(
        (lanesrc & 63) << 2, __float_as_int(v)));
}
__device__ __forceinline__ int bperm_i(int lanesrc, int v) {
    return __builtin_amdgcn_ds_bpermute((lanesrc & 63) << 2, v);
}

__global__ __launch_bounds__(64, 1)
void crf_llh_kernel(const float* __restrict__ em,      // (B,S,C)
                    const int*   __restrict__ tags,    // (B,S)
                    const int*   __restrict__ masks,   // (B,S)
                    const float* __restrict__ startT,  // (C)
                    const float* __restrict__ endT,    // (C)
                    const float* __restrict__ trans,   // (C,C)
                    float*       __restrict__ out)     // scalar
{
    const int b = blockIdx.x;
    const int l = threadIdx.x;      // 0..63
    const int c = l & 15;
    const int q = l >> 4;

    __shared__ __align__(16) float stage_em[4][1536];  // [stage][chain*96+k]
    __shared__ int   stage_mk[4][16];
    __shared__ float wl[CH * WLP];                     // transpose buffer

    // ---- B-frags: E[k][n] = exp(trans[k][n]); B: n=c, k=32*kt+8*q+j ----
    half8v Bf[3][6];
    #pragma unroll
    for (int kt = 0; kt < 3; ++kt) {
        #pragma unroll
        for (int nt = 0; nt < 6; ++nt) {
            #pragma unroll
            for (int jp = 0; jp < 4; ++jp) {
                const int k0 = 32 * kt + 8 * q + 2 * jp;
                const int n  = 16 * nt + c;
                const half2v pe = __builtin_amdgcn_cvt_pkrtz(
                    __expf(trans[(k0)     * NC + n]),
                    __expf(trans[(k0 + 1) * NC + n]));
                Bf[kt][nt][2 * jp]     = pe[0];
                Bf[kt][nt][2 * jp + 1] = pe[1];
            }
        }
    }

    // ---- per-lane DMA source bases: inst t covers flat slots 256t+4l..+3
    const float* gbase[6];
    #pragma unroll
    for (int t = 0; t < 6; ++t) {
        const int f  = 256 * t + 4 * l;
        const int ch = f / 96;
        const int kk = f - 96 * ch;
        gbase[t] = em + (size_t)(b * CH + ch) * SEQ * NC + kk;
    }
    const int* mkbase = masks + (size_t)(b * CH + (l & 15)) * SEQ;

    // ---- init: alpha0 = start + em[.,0,.]; exact per-chain max M0 ----
    const size_t gc = (size_t)(b * CH + c);
    const float* em_c = em + gc * SEQ * NC;
    const int*   mk_c = masks + gc * SEQ;
    const int*   tg_c = tags  + gc * SEQ;

    half8v Af[3];
    float M0;
    int   S;
    {
        float a0[24];
        float mx = -1e30f;
        #pragma unroll
        for (int kt = 0; kt < 3; ++kt)
            #pragma unroll
            for (int j = 0; j < 8; ++j) {
                const int k = 32 * kt + 8 * q + j;
                const float v = startT[k] + em_c[k];
                a0[kt * 8 + j] = v;
                mx = fmaxf(mx, v);
            }
        mx = fmaxf(mx, bperm_f(l ^ 16, mx));
        mx = fmaxf(mx, bperm_f(l ^ 32, mx));
        M0 = mx;
        S  = 1;
        #pragma unroll
        for (int kt = 0; kt < 3; ++kt)
            #pragma unroll
            for (int j = 0; j < 8; ++j)
                Af[kt][j] = (__fp16)(__expf(a0[kt * 8 + j] - M0) * 0.5f);
    }

    // ---- pre-issue DMA batches for steps 1 and 2 ----
    #pragma unroll
    for (int t = 0; t < 6; ++t)
        load_lds16(gbase[t] + (size_t)1 * NC, &stage_em[1][t * 256]);
    if (l < 16) load_lds4(mkbase + 1, &stage_mk[1][0]);
    #pragma unroll
    for (int t = 0; t < 6; ++t)
        load_lds16(gbase[t] + (size_t)2 * NC, &stage_em[2][t * 256]);
    if (l < 16) load_lds4(mkbase + 2, &stage_mk[2][0]);

    for (int s = 1; s < SEQ; ++s) {
        const int st  = s & 3;
        const int sp  = (s + 2 < SEQ) ? (s + 2) : (SEQ - 1);
        const int stp = (s + 2) & 3;

        // issue batch(s+2) -> stage[(s+2)%4]  (7 vm ops, async)
        #pragma unroll
        for (int t = 0; t < 6; ++t)
            load_lds16(gbase[t] + (size_t)sp * NC, &stage_em[stp][t * 256]);
        if (l < 16) load_lds4(mkbase + sp, &stage_mk[stp][0]);

        // batch(s) (issued 2 steps ago) must have landed: 14 newer ops allowed
        asm volatile("s_waitcnt vmcnt(14)" ::: "memory");

        // F for writer rows 4q+r, cols 16nt+c (reads issue early, exp off-path)
        float Fv[24];
        #pragma unroll
        for (int nt = 0; nt < 6; ++nt)
            #pragma unroll
            for (int r = 0; r < 4; ++r)
                Fv[nt * 4 + r] =
                    __expf(stage_em[st][(4 * q + r) * 96 + 16 * nt + c] - LN2X4);
        const int mk = stage_mk[st][c];

        // MFMA: U(16x96) = A·E; write w = U*F to wl (C-layout, f32)
        #pragma unroll
        for (int nt = 0; nt < 6; ++nt) {
            f32x4 a = {0.f, 0.f, 0.f, 0.f};
            a = __builtin_amdgcn_mfma_f32_16x16x32_f16(Af[0], Bf[0][nt], a, 0, 0, 0);
            a = __builtin_amdgcn_mfma_f32_16x16x32_f16(Af[1], Bf[1][nt], a, 0, 0, 0);
            a = __builtin_amdgcn_mfma_f32_16x16x32_f16(Af[2], Bf[2][nt], a, 0, 0, 0);
            #pragma unroll
            for (int r = 0; r < 4; ++r)
                wl[(4 * q + r) * WLP + 16 * nt + c] = a[r] * Fv[nt * 4 + r];
        }

        // readback row c in A-layout (in-order DS pipe: sees this step's writes)
        float wv[24];
        #pragma unroll
        for (int kt = 0; kt < 3; ++kt)
            #pragma unroll
            for (int j = 0; j < 8; ++j)
                wv[kt * 8 + j] = wl[c * WLP + 32 * kt + 8 * q + j];

        // full row max: local tree + xor16/xor32 exchange (lanes c,c+16,c+32,c+48)
        float mx = wv[0];
        #pragma unroll
        for (int i = 1; i < 24; ++i) mx = fmaxf(mx, wv[i]);
        mx = fmaxf(mx, bperm_f(l ^ 16, mx));
        mx = fmaxf(mx, bperm_f(l ^ 32, mx));

        // exact power-of-2 renorm; integer exponent sum
        const int eb = (int)((__float_as_uint(mx) >> 23) & 255u) - 126;
        half8v An[3];
        #pragma unroll
        for (int kt = 0; kt < 3; ++kt)
            #pragma unroll
            for (int jp = 0; jp < 4; ++jp) {
                const half2v p = __builtin_amdgcn_cvt_pkrtz(
                    ldexpf(wv[kt * 8 + 2 * jp],     -eb),
                    ldexpf(wv[kt * 8 + 2 * jp + 1], -eb));
                An[kt][2 * jp]     = p[0];
                An[kt][2 * jp + 1] = p[1];
            }
        if (mk) {
            Af[0] = An[0]; Af[1] = An[1]; Af[2] = An[2];
            S += eb + 4;   // +4: the 2^-4 folded into F
        }
    }

    // ---- denominator: M0 + S*ln2 + log(sum_k a_k * exp(end_k)) ----
    float dsum = 0.f;
    #pragma unroll
    for (int kt = 0; kt < 3; ++kt)
        #pragma unroll
        for (int j = 0; j < 8; ++j) {
            const int k = 32 * kt + 8 * q + j;
            dsum += (float)Af[kt][j] * __expf(endT[k]);
        }
    dsum += bperm_f(l ^ 16, dsum);
    dsum += bperm_f(l ^ 32, dsum);
    const float denom = M0 + (float)S * LN2 + __logf(dsum);

    // ---- numerator: tag-path gather; lane (c,q) does s in [128q,128q+128)
    float nsum = 0.f;
    int   cnt  = 0;
    {
        const int s0 = q * 128;
        int tprev = (s0 > 0) ? tg_c[s0 - 1] : 0;
        for (int i = 0; i < 128; ++i) {
            const int s  = s0 + i;
            const int tg = tg_c[s];
            const int mk = mk_c[s];
            cnt += mk ? 1 : 0;
            if (s == 0) {
                nsum += startT[tg] + em_c[tg];
            } else if (mk) {
                nsum += trans[tprev * NC + tg] + em_c[(size_t)s * NC + tg];
            }
            tprev = tg;
        }
    }
    nsum += bperm_f(l ^ 16, nsum);
    nsum += bperm_f(l ^ 32, nsum);
    cnt  += bperm_i(l ^ 16, cnt);
    cnt  += bperm_i(l ^ 32, cnt);

    float llh = 0.f;
    if (q == 0) {
        const int last = tg_c[cnt - 1];
        llh = (nsum + endT[last]) - denom;
    }
    const float tot = wave_sum_all(llh);
    if (l == 0) atomicAdd(out, tot * (1.0f / (float)BATCH));
}

extern "C" void kernel_launch(void* const* d_in, const int* in_sizes, int n_in,
                              void* d_out, int out_size, void* d_ws, size_t ws_size,
                              hipStream_t stream) {
    const float* em     = (const float*)d_in[0];
    const int*   tags   = (const int*)  d_in[1];
    const int*   masks  = (const int*)  d_in[2];
    const float* startT = (const float*)d_in[3];
    const float* endT   = (const float*)d_in[4];
    const float* trans  = (const float*)d_in[5];
    float* out = (float*)d_out;

    (void)hipMemsetAsync(out, 0, sizeof(float), stream);
    crf_llh_kernel<<<NBLK, 64, 0, stream>>>(em, tags, masks, startT, endT, trans, out);
}